// Round 1
// baseline (818.852 us; speedup 1.0000x reference)
//
#include <hip/hip_runtime.h>

#define N_NODES 50000
#define N_EDGES 800000
#define F_IN 128
#define DIM 256
#define N_GRAPHS 512
#define BN_EPS 1e-5f

typedef unsigned short u16;
typedef unsigned int u32;
using floatx4 = __attribute__((ext_vector_type(4))) float;
using short8 = __attribute__((ext_vector_type(8))) short;

__device__ __forceinline__ u16 f2b(float f) {
    u32 u = __float_as_uint(f);
    return (u16)((u + 0x7fffu + ((u >> 16) & 1u)) >> 16);
}
__device__ __forceinline__ float blo(u32 u) { return __uint_as_float(u << 16); }
__device__ __forceinline__ float bhi(u32 u) { return __uint_as_float(u & 0xffff0000u); }
__device__ __forceinline__ u32 pack2(float a, float b) {
    return (u32)f2b(a) | ((u32)f2b(b) << 16);
}
__device__ __forceinline__ void load_lds16(const void* g, void* l) {
    __builtin_amdgcn_global_load_lds((const __attribute__((address_space(1))) void*)g,
                                     (__attribute__((address_space(3))) void*)l, 16, 0, 0);
}

// ---------------- CSR build ----------------

__global__ void count_deg(const int* __restrict__ dst, int* __restrict__ deg, int nE) {
    int e = blockIdx.x * 256 + threadIdx.x;
    if (e < nE) atomicAdd(&deg[dst[e]], 1);
}

__global__ void scan_block(const int* __restrict__ deg, int* __restrict__ row_start,
                           int* __restrict__ bsum, int n) {
    __shared__ int wtot[4];
    int i = blockIdx.x * 256 + threadIdx.x;
    int lane = threadIdx.x & 63, w = threadIdx.x >> 6;
    int v = (i < n) ? deg[i] : 0;
    int s = v;
#pragma unroll
    for (int d = 1; d < 64; d <<= 1) {
        int t = __shfl_up(s, d);
        if (lane >= d) s += t;
    }
    if (lane == 63) wtot[w] = s;
    __syncthreads();
    int off = 0;
#pragma unroll
    for (int k = 0; k < 4; ++k)
        if (k < w) off += wtot[k];
    s += off;
    if (i < n) row_start[i + 1] = s;
    if (threadIdx.x == 255) bsum[blockIdx.x] = s;
}

__global__ void scan_partials(const int* __restrict__ bsum, int* __restrict__ boff,
                              int* __restrict__ row_start, int* __restrict__ cursor, int nb) {
    __shared__ int wtot[4];
    int i = threadIdx.x;
    int lane = i & 63, w = i >> 6;
    int v = (i < nb) ? bsum[i] : 0;
    int s = v;
#pragma unroll
    for (int d = 1; d < 64; d <<= 1) {
        int t = __shfl_up(s, d);
        if (lane >= d) s += t;
    }
    if (lane == 63) wtot[w] = s;
    __syncthreads();
    int off = 0;
#pragma unroll
    for (int k = 0; k < 4; ++k)
        if (k < w) off += wtot[k];
    boff[i] = s + off - v;
    if (i == 0) { row_start[0] = 0; cursor[0] = 0; }
}

__global__ void add_offsets(int* __restrict__ row_start, int* __restrict__ cursor,
                            const int* __restrict__ boff, int n) {
    int i = blockIdx.x * 256 + threadIdx.x;
    if (i < n) {
        int fin = row_start[i + 1] + boff[blockIdx.x];
        row_start[i + 1] = fin;
        cursor[i + 1] = fin;
    }
}

__global__ void fill_csr(const int* __restrict__ src, const int* __restrict__ dst,
                         int* __restrict__ cursor, int* __restrict__ srcs, int nE) {
    int e = blockIdx.x * 256 + threadIdx.x;
    if (e < nE) {
        int p = atomicAdd(&cursor[dst[e]], 1);
        srcs[p] = src[e];
    }
}

// ---------------- one-shot converts: x -> bf16 H, all 6 weights -> transposed bf16 ----------------
// segment bases (u16 elems in Wall): w1_0@0 (K=128), w1_1@32768, w1_2@98304,
// w2_0@163840, w2_1@229376, w2_2@294912 ; total 360448

__global__ void convert_all(const float4* __restrict__ x4, uint2* __restrict__ Hout, int n4,
                            const float* __restrict__ w10, const float* __restrict__ w11,
                            const float* __restrict__ w12, const float* __restrict__ w20,
                            const float* __restrict__ w21, const float* __restrict__ w22,
                            u16* __restrict__ Wall) {
    int i = blockIdx.x * 256 + threadIdx.x;
    if (i < n4) {
        float4 v = x4[i];
        uint2 p;
        p.x = pack2(v.x, v.y);
        p.y = pack2(v.z, v.w);
        Hout[i] = p;
        return;
    }
    int j = i - n4;
    if (j >= 360448) return;
    const float* w;
    int K, base;
    if (j < 32768)       { w = w10; K = 128; base = 0; }
    else if (j < 98304)  { w = w11; K = 256; base = 32768; }
    else if (j < 163840) { w = w12; K = 256; base = 98304; }
    else if (j < 229376) { w = w20; K = 256; base = 163840; }
    else if (j < 294912) { w = w21; K = 256; base = 229376; }
    else                 { w = w22; K = 256; base = 294912; }
    int loc = j - base;
    int nn = loc / K, kk = loc - nn * K;
    Wall[j] = f2b(w[(size_t)kk * 256 + nn]);
}

// ---------------- fused aggregate + GEMM1: T(64x256) = relu((h + sum_nbr h) @ W1^T + b1) ----------------
// 256 threads = 4 waves. Phase 1: each wave aggregates 16 rows (bf16 gather, fp32 acc) and
// writes the full 64xK A-panel into LDS, XOR-swizzled (16B chunk ^= row&7) so phase-2
// ds_read_b128 A-fragments are 2-way (free) instead of 16-way conflicted.
// Phase 2: K-loop stages only the W1 tile (global_load_lds) and runs 4x4 MFMA per wave.

template <int K>
__global__ __launch_bounds__(256, 3) void agg_gemm1(
    const u16* __restrict__ H, const int* __restrict__ row_start, const int* __restrict__ srcs,
    const u16* __restrict__ Bt, const float* __restrict__ bias,
    u16* __restrict__ Cout, int M) {
    __shared__ u16 Ap[64 * K];     // swizzled A panel (32KB or 16KB)
    __shared__ u16 Bs[256 * 32];   // W1 K-step tile (16KB)
    const int tid = threadIdx.x;
    const int w = tid >> 6, lane = tid & 63;
    const int r = lane & 15, rg = lane >> 4;
    const int bm = blockIdx.x * 64;
    constexpr int RB = K * 2;      // A-panel row bytes

    // ---- phase 1: aggregate ----
    for (int rr = 0; rr < 16; ++rr) {
        int m = w * 16 + rr;
        int node = bm + m;
        if (node >= M) node = M - 1;
        if constexpr (K == 256) {
            const uint2* hb = (const uint2*)H;   // 64 uint2 per row
            uint2 v = hb[(size_t)node * 64 + lane];
            float a0 = blo(v.x), a1 = bhi(v.x), a2 = blo(v.y), a3 = bhi(v.y);
            int s = row_start[node], e = row_start[node + 1];
            for (int j0 = s; j0 < e; j0 += 64) {
                int myidx = (j0 + lane < e) ? srcs[j0 + lane] : 0;
                int cnt = min(64, e - j0);
                int j = 0;
                for (; j + 7 < cnt; j += 8) {
                    uint2 g[8];
#pragma unroll
                    for (int q = 0; q < 8; ++q) {
                        int sq = __shfl(myidx, j + q);
                        g[q] = hb[(size_t)sq * 64 + lane];
                    }
#pragma unroll
                    for (int q = 0; q < 8; ++q) {
                        a0 += blo(g[q].x); a1 += bhi(g[q].x);
                        a2 += blo(g[q].y); a3 += bhi(g[q].y);
                    }
                }
                for (; j + 3 < cnt; j += 4) {
                    uint2 g[4];
#pragma unroll
                    for (int q = 0; q < 4; ++q) {
                        int sq = __shfl(myidx, j + q);
                        g[q] = hb[(size_t)sq * 64 + lane];
                    }
#pragma unroll
                    for (int q = 0; q < 4; ++q) {
                        a0 += blo(g[q].x); a1 += bhi(g[q].x);
                        a2 += blo(g[q].y); a3 += bhi(g[q].y);
                    }
                }
                for (; j < cnt; ++j) {
                    int sq = __shfl(myidx, j);
                    uint2 g0 = hb[(size_t)sq * 64 + lane];
                    a0 += blo(g0.x); a1 += bhi(g0.x);
                    a2 += blo(g0.y); a3 += bhi(g0.y);
                }
            }
            // lane covers elems [4*lane, 4*lane+4) = byte 8*lane -> chunk lane>>1, sub (lane&1)*8
            int ck = (lane >> 1) ^ (m & 7);
            char* lp = (char*)Ap + m * RB + (ck << 4) + (lane & 1) * 8;
            *(uint2*)lp = make_uint2(pack2(a0, a1), pack2(a2, a3));
        } else {
            const u32* hb = (const u32*)H;       // 64 u32 per row (K=128)
            u32 v = hb[(size_t)node * 64 + lane];
            float a0 = blo(v), a1 = bhi(v);
            int s = row_start[node], e = row_start[node + 1];
            for (int j0 = s; j0 < e; j0 += 64) {
                int myidx = (j0 + lane < e) ? srcs[j0 + lane] : 0;
                int cnt = min(64, e - j0);
                int j = 0;
                for (; j + 7 < cnt; j += 8) {
                    u32 g[8];
#pragma unroll
                    for (int q = 0; q < 8; ++q) {
                        int sq = __shfl(myidx, j + q);
                        g[q] = hb[(size_t)sq * 64 + lane];
                    }
#pragma unroll
                    for (int q = 0; q < 8; ++q) { a0 += blo(g[q]); a1 += bhi(g[q]); }
                }
                for (; j + 3 < cnt; j += 4) {
                    u32 g[4];
#pragma unroll
                    for (int q = 0; q < 4; ++q) {
                        int sq = __shfl(myidx, j + q);
                        g[q] = hb[(size_t)sq * 64 + lane];
                    }
#pragma unroll
                    for (int q = 0; q < 4; ++q) { a0 += blo(g[q]); a1 += bhi(g[q]); }
                }
                for (; j < cnt; ++j) {
                    int sq = __shfl(myidx, j);
                    u32 g0 = hb[(size_t)sq * 64 + lane];
                    a0 += blo(g0); a1 += bhi(g0);
                }
            }
            // lane covers elems [2*lane, 2*lane+2) = byte 4*lane -> chunk lane>>2, sub (lane&3)*4
            int ck = (lane >> 2) ^ (m & 7);
            char* lp = (char*)Ap + m * RB + (ck << 4) + (lane & 3) * 4;
            *(u32*)lp = pack2(a0, a1);
        }
    }

    // ---- phase 2: GEMM ----
    floatx4 acc[4][4];
#pragma unroll
    for (int i = 0; i < 4; ++i)
#pragma unroll
        for (int j = 0; j < 4; ++j) acc[i][j] = (floatx4){0.f, 0.f, 0.f, 0.f};

    for (int k0 = 0; k0 < K; k0 += 32) {
        __syncthreads();  // Ap ready (1st iter) / Bs consumed (later iters)
#pragma unroll
        for (int q = 0; q < 4; ++q) {
            int i = q * 256 + tid;
            int nrow = i >> 2;
            load_lds16(Bt + (size_t)nrow * K + k0 + (i & 3) * 8, Bs + (q * 4 + w) * 512);
        }
        __syncthreads();
        short8 a[4], b[4];
#pragma unroll
        for (int mi = 0; mi < 4; ++mi) {
            int m = mi * 16 + r;
            int ck = ((k0 >> 3) + rg) ^ (m & 7);
            a[mi] = *(const short8*)((const char*)Ap + m * RB + (ck << 4));
        }
#pragma unroll
        for (int ni = 0; ni < 4; ++ni)
            b[ni] = *(const short8*)(Bs + (w * 64 + ni * 16 + r) * 32 + rg * 8);
#pragma unroll
        for (int mi = 0; mi < 4; ++mi)
#pragma unroll
            for (int ni = 0; ni < 4; ++ni)
                acc[mi][ni] = __builtin_amdgcn_mfma_f32_16x16x32_bf16(a[mi], b[ni], acc[mi][ni], 0, 0, 0);
    }

    u16* C = (u16*)Cout;
#pragma unroll
    for (int ni = 0; ni < 4; ++ni) {
        int col = w * 64 + ni * 16 + r;
        float bv = bias[col];
#pragma unroll
        for (int mi = 0; mi < 4; ++mi)
#pragma unroll
            for (int rr2 = 0; rr2 < 4; ++rr2) {
                int row = bm + mi * 16 + rg * 4 + rr2;
                if (row < M) C[(size_t)row * 256 + col] = f2b(fmaxf(acc[mi][ni][rr2] + bv, 0.f));
            }
    }
}

// ---------------- bf16 MFMA GEMM, full-N: C(128x256) = relu(A @ Wt^T + bias) ----------------
// 512 threads = 8 waves (2 m x 4 n), wave tile 64x64 (4x4 frags of 16x16x32)
// MODE 1: C fp32 out + fused BN partial sums. (MODE 0 path retired; GEMM1 is fused above.)

template <int MODE>
__global__ __launch_bounds__(512) void gemm_mfma(
    const u16* __restrict__ A, const u16* __restrict__ Bt, const float* __restrict__ bias,
    void* __restrict__ Cout, float* __restrict__ sums, int M, int K) {
    __shared__ u16 As[128 * 32];
    __shared__ u16 Bs[256 * 32];
    const int tid = threadIdx.x;
    const int w = tid >> 6, lane = tid & 63;
    const int wm = w >> 2, wn = w & 3;
    const int r = lane & 15, rg = lane >> 4;
    const int bm = blockIdx.x * 128;

    floatx4 acc[4][4];
#pragma unroll
    for (int i = 0; i < 4; ++i)
#pragma unroll
        for (int j = 0; j < 4; ++j) acc[i][j] = (floatx4){0.f, 0.f, 0.f, 0.f};

    for (int k0 = 0; k0 < K; k0 += 32) {
        __syncthreads();
        {
            int arow = bm + (tid >> 2);
            if (arow >= M) arow = M - 1;
            load_lds16(A + (size_t)arow * K + k0 + (tid & 3) * 8, As + w * 512);
#pragma unroll
            for (int q = 0; q < 2; ++q) {
                int i = q * 512 + tid;
                int nrow = i >> 2;
                load_lds16(Bt + (size_t)nrow * K + k0 + (i & 3) * 8, Bs + (q * 8 + w) * 512);
            }
        }
        __syncthreads();
        short8 a[4], b[4];
#pragma unroll
        for (int mi = 0; mi < 4; ++mi)
            a[mi] = *(const short8*)(As + (wm * 64 + mi * 16 + r) * 32 + rg * 8);
#pragma unroll
        for (int ni = 0; ni < 4; ++ni)
            b[ni] = *(const short8*)(Bs + (wn * 64 + ni * 16 + r) * 32 + rg * 8);
#pragma unroll
        for (int mi = 0; mi < 4; ++mi)
#pragma unroll
            for (int ni = 0; ni < 4; ++ni)
                acc[mi][ni] = __builtin_amdgcn_mfma_f32_16x16x32_bf16(a[mi], b[ni], acc[mi][ni], 0, 0, 0);
    }

    if (MODE == 0) {
        u16* C = (u16*)Cout;
#pragma unroll
        for (int ni = 0; ni < 4; ++ni) {
            int col = wn * 64 + ni * 16 + r;
            float bv = bias[col];
#pragma unroll
            for (int mi = 0; mi < 4; ++mi)
#pragma unroll
                for (int rr = 0; rr < 4; ++rr) {
                    int row = bm + wm * 64 + mi * 16 + rg * 4 + rr;
                    if (row < M) C[(size_t)row * 256 + col] = f2b(fmaxf(acc[mi][ni][rr] + bv, 0.f));
                }
        }
    } else {
        float* C = (float*)Cout;
#pragma unroll
        for (int ni = 0; ni < 4; ++ni) {
            int col = wn * 64 + ni * 16 + r;
            float bv = bias[col];
            float s = 0.f, s2 = 0.f;
#pragma unroll
            for (int mi = 0; mi < 4; ++mi)
#pragma unroll
                for (int rr = 0; rr < 4; ++rr) {
                    int row = bm + wm * 64 + mi * 16 + rg * 4 + rr;
                    if (row < M) {
                        float v = fmaxf(acc[mi][ni][rr] + bv, 0.f);
                        C[(size_t)row * 256 + col] = v;
                        s += v;
                        s2 += v * v;
                    }
                }
            s += __shfl_xor(s, 16);
            s += __shfl_xor(s, 32);
            s2 += __shfl_xor(s2, 16);
            s2 += __shfl_xor(s2, 32);
            if (rg == 0) {
                atomicAdd(&sums[col], s);
                atomicAdd(&sums[256 + col], s2);
            }
        }
    }
}

// ---------------- BN finalize+apply + bf16 re-pack + fused per-graph pooling ----------------

template <int WRITE_H>
__global__ void bn_apply_pool(const float* __restrict__ Mfp, const float* __restrict__ sums,
                              const float* __restrict__ g, const float* __restrict__ bb,
                              const int* __restrict__ batch, float* __restrict__ out_nodes,
                              u16* __restrict__ H, float* __restrict__ pooled,
                              int col_off, int n, float inv_n) {
    int w = threadIdx.x >> 6, lane = threadIdx.x & 63;
    int base = blockIdx.x * 64 + w * 16;
    if (base >= n) return;
    int c4 = lane << 2;
    float4 s1 = *(const float4*)(sums + c4);
    float4 s2 = *(const float4*)(sums + 256 + c4);
    float4 g4 = *(const float4*)(g + c4);
    float4 b4 = *(const float4*)(bb + c4);
    float4 sc, sh;
    {
        float mux = s1.x * inv_n, muy = s1.y * inv_n, muz = s1.z * inv_n, muw = s1.w * inv_n;
        sc.x = g4.x / sqrtf(s2.x * inv_n - mux * mux + BN_EPS);
        sc.y = g4.y / sqrtf(s2.y * inv_n - muy * muy + BN_EPS);
        sc.z = g4.z / sqrtf(s2.z * inv_n - muz * muz + BN_EPS);
        sc.w = g4.w / sqrtf(s2.w * inv_n - muw * muw + BN_EPS);
        sh.x = b4.x - mux * sc.x;
        sh.y = b4.y - muy * sc.y;
        sh.z = b4.z - muz * sc.z;
        sh.w = b4.w - muw * sc.w;
    }
    float4 acc = make_float4(0.f, 0.f, 0.f, 0.f);
    int gcur = -1;
    int end = min(base + 16, n);
    for (int row = base; row < end; ++row) {
        float4 v = *(const float4*)(Mfp + (size_t)row * 256 + c4);
        float4 o;
        o.x = fmaf(v.x, sc.x, sh.x);
        o.y = fmaf(v.y, sc.y, sh.y);
        o.z = fmaf(v.z, sc.z, sh.z);
        o.w = fmaf(v.w, sc.w, sh.w);
        *(float4*)(out_nodes + (size_t)row * 768 + col_off + c4) = o;
        if (WRITE_H) {
            uint2 pk;
            pk.x = pack2(o.x, o.y);
            pk.y = pack2(o.z, o.w);
            *(uint2*)(H + (size_t)row * 256 + c4) = pk;
        }
        int gg = batch[row];
        if (gg != gcur) {
            if (gcur >= 0) {
                float* pp = pooled + (size_t)gcur * 768 + col_off + c4;
                atomicAdd(pp + 0, acc.x);
                atomicAdd(pp + 1, acc.y);
                atomicAdd(pp + 2, acc.z);
                atomicAdd(pp + 3, acc.w);
            }
            gcur = gg;
            acc = o;
        } else {
            acc.x += o.x; acc.y += o.y; acc.z += o.z; acc.w += o.w;
        }
    }
    if (gcur >= 0) {
        float* pp = pooled + (size_t)gcur * 768 + col_off + c4;
        atomicAdd(pp + 0, acc.x);
        atomicAdd(pp + 1, acc.y);
        atomicAdd(pp + 2, acc.z);
        atomicAdd(pp + 3, acc.w);
    }
}

// ---------------- launch ----------------

extern "C" void kernel_launch(void* const* d_in, const int* in_sizes, int n_in,
                              void* d_out, int out_size, void* d_ws, size_t ws_size,
                              hipStream_t stream) {
    const float* x = (const float*)d_in[0];
    const int* esrc = (const int*)d_in[1];
    const int* edst = esrc + N_EDGES;
    const int* batch = (const int*)d_in[2];

    const float* w1[3] = {(const float*)d_in[3], (const float*)d_in[9], (const float*)d_in[15]};
    const float* b1[3] = {(const float*)d_in[4], (const float*)d_in[10], (const float*)d_in[16]};
    const float* w2[3] = {(const float*)d_in[5], (const float*)d_in[11], (const float*)d_in[17]};
    const float* b2[3] = {(const float*)d_in[6], (const float*)d_in[12], (const float*)d_in[18]};
    const float* bng[3] = {(const float*)d_in[7], (const float*)d_in[13], (const float*)d_in[19]};
    const float* bnb[3] = {(const float*)d_in[8], (const float*)d_in[14], (const float*)d_in[20]};

    float* out_pooled = (float*)d_out;
    float* out_nodes = (float*)d_out + (size_t)N_GRAPHS * 768;

    char* p = (char*)d_ws;
    float* Mfp = (float*)p;            // 50000*256 fp32 (GEMM2 out)
    p += (size_t)N_NODES * 256 * 4;
    u16* T = (u16*)p;  p += (size_t)N_NODES * 256 * 2;   // fused agg+GEMM1 out
    u16* H = (u16*)p;  p += (size_t)N_NODES * 256 * 2;   // bf16 node feats
    u16* Wall = (u16*)p; p += (size_t)360448 * 2;        // all transposed weights
    // zero region: [sums x3 | deg]  (one memset)
    float* sums = (float*)p; p += 3 * 512 * 4;
    int* deg = (int*)p;      p += (size_t)N_NODES * 4;
    const size_t zero_bytes = 3 * 512 * 4 + (size_t)N_NODES * 4;
    int* row_start = (int*)p; p += (size_t)(N_NODES + 1) * 4;
    int* cursor = (int*)p;    p += (size_t)(N_NODES + 1) * 4;
    int* srcs = (int*)p;      p += (size_t)N_EDGES * 4;
    int* bsum = (int*)p;      p += 256 * 4;
    int* boff = (int*)p;      p += 256 * 4;

    const u16* W1t[3] = {Wall, Wall + 32768, Wall + 98304};
    const u16* W2t[3] = {Wall + 163840, Wall + 229376, Wall + 294912};

    const int NBLK = (N_NODES + 255) / 256;  // 196

    hipMemsetAsync(sums, 0, zero_bytes, stream);
    hipMemsetAsync(out_pooled, 0, (size_t)N_GRAPHS * 768 * sizeof(float), stream);

    // CSR build
    count_deg<<<(N_EDGES + 255) / 256, 256, 0, stream>>>(edst, deg, N_EDGES);
    scan_block<<<NBLK, 256, 0, stream>>>(deg, row_start, bsum, N_NODES);
    scan_partials<<<1, 256, 0, stream>>>(bsum, boff, row_start, cursor, NBLK);
    add_offsets<<<NBLK, 256, 0, stream>>>(row_start, cursor, boff, N_NODES);
    fill_csr<<<(N_EDGES + 255) / 256, 256, 0, stream>>>(esrc, edst, cursor, srcs, N_EDGES);

    // all dtype converts in one kernel
    {
        const int n4 = N_NODES * F_IN / 4;  // 1,600,000 float4s
        const int tot = n4 + 360448;
        convert_all<<<(tot + 255) / 256, 256, 0, stream>>>(
            (const float4*)x, (uint2*)H, n4,
            w1[0], w1[1], w1[2], w2[0], w2[1], w2[2], Wall);
    }

    const int FGRID = (N_NODES + 63) / 64;    // 782 (fused agg+GEMM1)
    const int GGRID = (N_NODES + 127) / 128;  // 391 (GEMM2)
    const int PBLK = (N_NODES + 63) / 64;     // 782
    for (int L = 0; L < 3; ++L) {
        float* sumsL = sums + L * 512;
        if (L == 0)
            agg_gemm1<128><<<FGRID, 256, 0, stream>>>(H, row_start, srcs, W1t[L], b1[L], T, N_NODES);
        else
            agg_gemm1<256><<<FGRID, 256, 0, stream>>>(H, row_start, srcs, W1t[L], b1[L], T, N_NODES);
        gemm_mfma<1><<<GGRID, 512, 0, stream>>>(T, W2t[L], b2[L], (void*)Mfp, sumsL, N_NODES, DIM);
        if (L < 2)
            bn_apply_pool<1><<<PBLK, 256, 0, stream>>>(Mfp, sumsL, bng[L], bnb[L], batch,
                                                       out_nodes, H, out_pooled, L * 256, N_NODES, 1.0f / N_NODES);
        else
            bn_apply_pool<0><<<PBLK, 256, 0, stream>>>(Mfp, sumsL, bng[L], bnb[L], batch,
                                                       out_nodes, H, out_pooled, L * 256, N_NODES, 1.0f / N_NODES);
    }
}

// Round 2
// 705.872 us; speedup vs baseline: 1.1601x; 1.1601x over previous
//
#include <hip/hip_runtime.h>

#define N_NODES 50000
#define N_EDGES 800000
#define F_IN 128
#define DIM 256
#define N_GRAPHS 512
#define BN_EPS 1e-5f

typedef unsigned short u16;
typedef unsigned int u32;
using floatx4 = __attribute__((ext_vector_type(4))) float;
using short8 = __attribute__((ext_vector_type(8))) short;

__device__ __forceinline__ u16 f2b(float f) {
    u32 u = __float_as_uint(f);
    return (u16)((u + 0x7fffu + ((u >> 16) & 1u)) >> 16);
}
__device__ __forceinline__ float blo(u32 u) { return __uint_as_float(u << 16); }
__device__ __forceinline__ float bhi(u32 u) { return __uint_as_float(u & 0xffff0000u); }
__device__ __forceinline__ u32 pack2(float a, float b) {
    return (u32)f2b(a) | ((u32)f2b(b) << 16);
}
__device__ __forceinline__ void load_lds16(const void* g, void* l) {
    __builtin_amdgcn_global_load_lds((const __attribute__((address_space(1))) void*)g,
                                     (__attribute__((address_space(3))) void*)l, 16, 0, 0);
}

// ---------------- CSR build ----------------

__global__ void count_deg(const int* __restrict__ dst, int* __restrict__ deg, int nE) {
    int e = blockIdx.x * 256 + threadIdx.x;
    if (e < nE) atomicAdd(&deg[dst[e]], 1);
}

__global__ void scan_block(const int* __restrict__ deg, int* __restrict__ row_start,
                           int* __restrict__ bsum, int n) {
    __shared__ int wtot[4];
    int i = blockIdx.x * 256 + threadIdx.x;
    int lane = threadIdx.x & 63, w = threadIdx.x >> 6;
    int v = (i < n) ? deg[i] : 0;
    int s = v;
#pragma unroll
    for (int d = 1; d < 64; d <<= 1) {
        int t = __shfl_up(s, d);
        if (lane >= d) s += t;
    }
    if (lane == 63) wtot[w] = s;
    __syncthreads();
    int off = 0;
#pragma unroll
    for (int k = 0; k < 4; ++k)
        if (k < w) off += wtot[k];
    s += off;
    if (i < n) row_start[i + 1] = s;
    if (threadIdx.x == 255) bsum[blockIdx.x] = s;
}

__global__ void scan_partials(const int* __restrict__ bsum, int* __restrict__ boff,
                              int* __restrict__ row_start, int* __restrict__ cursor, int nb) {
    __shared__ int wtot[4];
    int i = threadIdx.x;
    int lane = i & 63, w = i >> 6;
    int v = (i < nb) ? bsum[i] : 0;
    int s = v;
#pragma unroll
    for (int d = 1; d < 64; d <<= 1) {
        int t = __shfl_up(s, d);
        if (lane >= d) s += t;
    }
    if (lane == 63) wtot[w] = s;
    __syncthreads();
    int off = 0;
#pragma unroll
    for (int k = 0; k < 4; ++k)
        if (k < w) off += wtot[k];
    boff[i] = s + off - v;
    if (i == 0) { row_start[0] = 0; cursor[0] = 0; }
}

__global__ void add_offsets(int* __restrict__ row_start, int* __restrict__ cursor,
                            const int* __restrict__ boff, int n) {
    int i = blockIdx.x * 256 + threadIdx.x;
    if (i < n) {
        int fin = row_start[i + 1] + boff[blockIdx.x];
        row_start[i + 1] = fin;
        cursor[i + 1] = fin;
    }
}

__global__ void fill_csr(const int* __restrict__ src, const int* __restrict__ dst,
                         int* __restrict__ cursor, int* __restrict__ srcs, int nE) {
    int e = blockIdx.x * 256 + threadIdx.x;
    if (e < nE) {
        int p = atomicAdd(&cursor[dst[e]], 1);
        srcs[p] = src[e];
    }
}

// ---------------- one-shot converts: x -> bf16 H, all 6 weights -> transposed bf16 ----------------
// segment bases (u16 elems in Wall): w1_0@0 (K=128), w1_1@32768, w1_2@98304,
// w2_0@163840, w2_1@229376, w2_2@294912 ; total 360448

__global__ void convert_all(const float4* __restrict__ x4, uint2* __restrict__ Hout, int n4,
                            const float* __restrict__ w10, const float* __restrict__ w11,
                            const float* __restrict__ w12, const float* __restrict__ w20,
                            const float* __restrict__ w21, const float* __restrict__ w22,
                            u16* __restrict__ Wall) {
    int i = blockIdx.x * 256 + threadIdx.x;
    if (i < n4) {
        float4 v = x4[i];
        uint2 p;
        p.x = pack2(v.x, v.y);
        p.y = pack2(v.z, v.w);
        Hout[i] = p;
        return;
    }
    int j = i - n4;
    if (j >= 360448) return;
    const float* w;
    int K, base;
    if (j < 32768)       { w = w10; K = 128; base = 0; }
    else if (j < 98304)  { w = w11; K = 256; base = 32768; }
    else if (j < 163840) { w = w12; K = 256; base = 98304; }
    else if (j < 229376) { w = w20; K = 256; base = 163840; }
    else if (j < 294912) { w = w21; K = 256; base = 229376; }
    else                 { w = w22; K = 256; base = 294912; }
    int loc = j - base;
    int nn = loc / K, kk = loc - nn * K;
    Wall[j] = f2b(w[(size_t)kk * 256 + nn]);
}

// ---------------- aggregation v2 (bf16 gather): agg = h_i + sum_j h_j ----------------
// One wave per node. Multi-row gather instructions: lanes split into NSUB row-groups,
// each group reads a DIFFERENT neighbor row as uint4 (16B/lane) -> 1KiB per instruction
// (vs 512B/256B before). Per-lane partial sums folded with shfl_xor at the end.
// Halves (K=256) / quarters (K=128) the gather instruction count; same bytes, same ILP.

template <int K>
__global__ __launch_bounds__(256) void aggregate_v2(
    const u16* __restrict__ h, const int* __restrict__ row_start,
    const int* __restrict__ srcs, u16* __restrict__ outp, int n) {
    constexpr int RW = K / 2;                 // u32 per row (128 or 64)
    constexpr int NSUB = (K == 256) ? 2 : 4;  // rows per gather instruction
    constexpr int NI = 8 / NSUB;              // instructions per 8-row batch
    int node = (int)(((size_t)blockIdx.x * blockDim.x + threadIdx.x) >> 6);
    int lane = threadIdx.x & 63;
    if (node >= n) return;
    const u32* hb = (const u32*)h;
    const int sub = lane / (64 / NSUB);       // row-group within the wave
    const int li = lane % (64 / NSUB);        // 16B chunk index within row

    float acc[8];
    {
        // self row: only the sub==0 lanes contribute (others init 0)
        uint4 v = make_uint4(0u, 0u, 0u, 0u);
        if (sub == 0) v = *(const uint4*)(hb + (size_t)node * RW + li * 4);
        acc[0] = blo(v.x); acc[1] = bhi(v.x);
        acc[2] = blo(v.y); acc[3] = bhi(v.y);
        acc[4] = blo(v.z); acc[5] = bhi(v.z);
        acc[6] = blo(v.w); acc[7] = bhi(v.w);
    }

    int s = row_start[node], e = row_start[node + 1];
    for (int j0 = s; j0 < e; j0 += 64) {
        int myidx = (j0 + lane < e) ? srcs[j0 + lane] : 0;
        int cnt = min(64, e - j0);
        int j = 0;
        for (; j + 7 < cnt; j += 8) {  // 8 neighbor rows in flight, NI instructions
            uint4 g[NI];
#pragma unroll
            for (int q = 0; q < NI; ++q) {
                int sq = __shfl(myidx, j + q * NSUB + sub);
                g[q] = *(const uint4*)(hb + (size_t)sq * RW + li * 4);
            }
#pragma unroll
            for (int q = 0; q < NI; ++q) {
                acc[0] += blo(g[q].x); acc[1] += bhi(g[q].x);
                acc[2] += blo(g[q].y); acc[3] += bhi(g[q].y);
                acc[4] += blo(g[q].z); acc[5] += bhi(g[q].z);
                acc[6] += blo(g[q].w); acc[7] += bhi(g[q].w);
            }
        }
        for (; j < cnt; j += NSUB) {  // predicated remainder, NSUB rows at a time
            int idx = j + sub;
            bool valid = idx < cnt;
            int sq = __shfl(myidx, valid ? idx : j);
            if (valid) {
                uint4 g = *(const uint4*)(hb + (size_t)sq * RW + li * 4);
                acc[0] += blo(g.x); acc[1] += bhi(g.x);
                acc[2] += blo(g.y); acc[3] += bhi(g.y);
                acc[4] += blo(g.z); acc[5] += bhi(g.z);
                acc[6] += blo(g.w); acc[7] += bhi(g.w);
            }
        }
    }

    // fold partial sums across row-groups
    if (NSUB == 4) {
#pragma unroll
        for (int t = 0; t < 8; ++t) acc[t] += __shfl_xor(acc[t], 16);
    }
#pragma unroll
    for (int t = 0; t < 8; ++t) acc[t] += __shfl_xor(acc[t], 32);

    if (sub == 0) {
        uint4 o;
        o.x = pack2(acc[0], acc[1]);
        o.y = pack2(acc[2], acc[3]);
        o.z = pack2(acc[4], acc[5]);
        o.w = pack2(acc[6], acc[7]);
        *(uint4*)((u32*)outp + (size_t)node * RW + li * 4) = o;
    }
}

// ---------------- bf16 MFMA GEMM, full-N: C(128x256) = relu(A @ Wt^T + bias) ----------------
// 512 threads = 8 waves (2 m x 4 n), wave tile 64x64 (4x4 frags of 16x16x32)
// MODE 0: C bf16 out.  MODE 1: C fp32 out + fused BN partial sums.

template <int MODE>
__global__ __launch_bounds__(512) void gemm_mfma(
    const u16* __restrict__ A, const u16* __restrict__ Bt, const float* __restrict__ bias,
    void* __restrict__ Cout, float* __restrict__ sums, int M, int K) {
    __shared__ u16 As[128 * 32];
    __shared__ u16 Bs[256 * 32];
    const int tid = threadIdx.x;
    const int w = tid >> 6, lane = tid & 63;
    const int wm = w >> 2, wn = w & 3;
    const int r = lane & 15, rg = lane >> 4;
    const int bm = blockIdx.x * 128;

    floatx4 acc[4][4];
#pragma unroll
    for (int i = 0; i < 4; ++i)
#pragma unroll
        for (int j = 0; j < 4; ++j) acc[i][j] = (floatx4){0.f, 0.f, 0.f, 0.f};

    for (int k0 = 0; k0 < K; k0 += 32) {
        __syncthreads();
        {
            int arow = bm + (tid >> 2);
            if (arow >= M) arow = M - 1;
            load_lds16(A + (size_t)arow * K + k0 + (tid & 3) * 8, As + w * 512);
#pragma unroll
            for (int q = 0; q < 2; ++q) {
                int i = q * 512 + tid;
                int nrow = i >> 2;
                load_lds16(Bt + (size_t)nrow * K + k0 + (i & 3) * 8, Bs + (q * 8 + w) * 512);
            }
        }
        __syncthreads();
        short8 a[4], b[4];
#pragma unroll
        for (int mi = 0; mi < 4; ++mi)
            a[mi] = *(const short8*)(As + (wm * 64 + mi * 16 + r) * 32 + rg * 8);
#pragma unroll
        for (int ni = 0; ni < 4; ++ni)
            b[ni] = *(const short8*)(Bs + (wn * 64 + ni * 16 + r) * 32 + rg * 8);
#pragma unroll
        for (int mi = 0; mi < 4; ++mi)
#pragma unroll
            for (int ni = 0; ni < 4; ++ni)
                acc[mi][ni] = __builtin_amdgcn_mfma_f32_16x16x32_bf16(a[mi], b[ni], acc[mi][ni], 0, 0, 0);
    }

    if (MODE == 0) {
        u16* C = (u16*)Cout;
#pragma unroll
        for (int ni = 0; ni < 4; ++ni) {
            int col = wn * 64 + ni * 16 + r;
            float bv = bias[col];
#pragma unroll
            for (int mi = 0; mi < 4; ++mi)
#pragma unroll
                for (int rr = 0; rr < 4; ++rr) {
                    int row = bm + wm * 64 + mi * 16 + rg * 4 + rr;
                    if (row < M) C[(size_t)row * 256 + col] = f2b(fmaxf(acc[mi][ni][rr] + bv, 0.f));
                }
        }
    } else {
        float* C = (float*)Cout;
#pragma unroll
        for (int ni = 0; ni < 4; ++ni) {
            int col = wn * 64 + ni * 16 + r;
            float bv = bias[col];
            float s = 0.f, s2 = 0.f;
#pragma unroll
            for (int mi = 0; mi < 4; ++mi)
#pragma unroll
                for (int rr = 0; rr < 4; ++rr) {
                    int row = bm + wm * 64 + mi * 16 + rg * 4 + rr;
                    if (row < M) {
                        float v = fmaxf(acc[mi][ni][rr] + bv, 0.f);
                        C[(size_t)row * 256 + col] = v;
                        s += v;
                        s2 += v * v;
                    }
                }
            s += __shfl_xor(s, 16);
            s += __shfl_xor(s, 32);
            s2 += __shfl_xor(s2, 16);
            s2 += __shfl_xor(s2, 32);
            if (rg == 0) {
                atomicAdd(&sums[col], s);
                atomicAdd(&sums[256 + col], s2);
            }
        }
    }
}

// ---------------- BN finalize+apply + bf16 re-pack + fused per-graph pooling ----------------
// Mfp read and out_nodes write are nontemporal (read-once / write-only) to keep H hot
// in L2/L3 for the next layer's gather.

template <int WRITE_H>
__global__ void bn_apply_pool(const float* __restrict__ Mfp, const float* __restrict__ sums,
                              const float* __restrict__ g, const float* __restrict__ bb,
                              const int* __restrict__ batch, float* __restrict__ out_nodes,
                              u16* __restrict__ H, float* __restrict__ pooled,
                              int col_off, int n, float inv_n) {
    int w = threadIdx.x >> 6, lane = threadIdx.x & 63;
    int base = blockIdx.x * 64 + w * 16;
    if (base >= n) return;
    int c4 = lane << 2;
    float4 s1 = *(const float4*)(sums + c4);
    float4 s2 = *(const float4*)(sums + 256 + c4);
    float4 g4 = *(const float4*)(g + c4);
    float4 b4 = *(const float4*)(bb + c4);
    float4 sc, sh;
    {
        float mux = s1.x * inv_n, muy = s1.y * inv_n, muz = s1.z * inv_n, muw = s1.w * inv_n;
        sc.x = g4.x / sqrtf(s2.x * inv_n - mux * mux + BN_EPS);
        sc.y = g4.y / sqrtf(s2.y * inv_n - muy * muy + BN_EPS);
        sc.z = g4.z / sqrtf(s2.z * inv_n - muz * muz + BN_EPS);
        sc.w = g4.w / sqrtf(s2.w * inv_n - muw * muw + BN_EPS);
        sh.x = b4.x - mux * sc.x;
        sh.y = b4.y - muy * sc.y;
        sh.z = b4.z - muz * sc.z;
        sh.w = b4.w - muw * sc.w;
    }
    float4 acc = make_float4(0.f, 0.f, 0.f, 0.f);
    int gcur = -1;
    int end = min(base + 16, n);
    for (int row = base; row < end; ++row) {
        floatx4 vv = __builtin_nontemporal_load((const floatx4*)(Mfp + (size_t)row * 256 + c4));
        float4 o;
        o.x = fmaf(vv.x, sc.x, sh.x);
        o.y = fmaf(vv.y, sc.y, sh.y);
        o.z = fmaf(vv.z, sc.z, sh.z);
        o.w = fmaf(vv.w, sc.w, sh.w);
        floatx4 ov = {o.x, o.y, o.z, o.w};
        __builtin_nontemporal_store(ov, (floatx4*)(out_nodes + (size_t)row * 768 + col_off + c4));
        if (WRITE_H) {
            uint2 pk;
            pk.x = pack2(o.x, o.y);
            pk.y = pack2(o.z, o.w);
            *(uint2*)(H + (size_t)row * 256 + c4) = pk;
        }
        int gg = batch[row];
        if (gg != gcur) {
            if (gcur >= 0) {
                float* pp = pooled + (size_t)gcur * 768 + col_off + c4;
                atomicAdd(pp + 0, acc.x);
                atomicAdd(pp + 1, acc.y);
                atomicAdd(pp + 2, acc.z);
                atomicAdd(pp + 3, acc.w);
            }
            gcur = gg;
            acc = o;
        } else {
            acc.x += o.x; acc.y += o.y; acc.z += o.z; acc.w += o.w;
        }
    }
    if (gcur >= 0) {
        float* pp = pooled + (size_t)gcur * 768 + col_off + c4;
        atomicAdd(pp + 0, acc.x);
        atomicAdd(pp + 1, acc.y);
        atomicAdd(pp + 2, acc.z);
        atomicAdd(pp + 3, acc.w);
    }
}

// ---------------- launch ----------------

extern "C" void kernel_launch(void* const* d_in, const int* in_sizes, int n_in,
                              void* d_out, int out_size, void* d_ws, size_t ws_size,
                              hipStream_t stream) {
    const float* x = (const float*)d_in[0];
    const int* esrc = (const int*)d_in[1];
    const int* edst = esrc + N_EDGES;
    const int* batch = (const int*)d_in[2];

    const float* w1[3] = {(const float*)d_in[3], (const float*)d_in[9], (const float*)d_in[15]};
    const float* b1[3] = {(const float*)d_in[4], (const float*)d_in[10], (const float*)d_in[16]};
    const float* w2[3] = {(const float*)d_in[5], (const float*)d_in[11], (const float*)d_in[17]};
    const float* b2[3] = {(const float*)d_in[6], (const float*)d_in[12], (const float*)d_in[18]};
    const float* bng[3] = {(const float*)d_in[7], (const float*)d_in[13], (const float*)d_in[19]};
    const float* bnb[3] = {(const float*)d_in[8], (const float*)d_in[14], (const float*)d_in[20]};

    float* out_pooled = (float*)d_out;
    float* out_nodes = (float*)d_out + (size_t)N_GRAPHS * 768;

    char* p = (char*)d_ws;
    float* Mfp = (float*)p;            // 50000*256 fp32 (GEMM2 out)
    u16* Abf = (u16*)p;                // aliases Mfp (disjoint in time)
    p += (size_t)N_NODES * 256 * 4;
    u16* T = (u16*)p;  p += (size_t)N_NODES * 256 * 2;   // GEMM1 out
    u16* H = (u16*)p;  p += (size_t)N_NODES * 256 * 2;   // bf16 node feats
    u16* Wall = (u16*)p; p += (size_t)360448 * 2;        // all transposed weights
    // zero region: [sums x3 | deg]  (one memset)
    float* sums = (float*)p; p += 3 * 512 * 4;
    int* deg = (int*)p;      p += (size_t)N_NODES * 4;
    const size_t zero_bytes = 3 * 512 * 4 + (size_t)N_NODES * 4;
    int* row_start = (int*)p; p += (size_t)(N_NODES + 1) * 4;
    int* cursor = (int*)p;    p += (size_t)(N_NODES + 1) * 4;
    int* srcs = (int*)p;      p += (size_t)N_EDGES * 4;
    int* bsum = (int*)p;      p += 256 * 4;
    int* boff = (int*)p;      p += 256 * 4;

    const u16* W1t[3] = {Wall, Wall + 32768, Wall + 98304};
    const u16* W2t[3] = {Wall + 163840, Wall + 229376, Wall + 294912};

    const int NBLK = (N_NODES + 255) / 256;  // 196

    hipMemsetAsync(sums, 0, zero_bytes, stream);
    hipMemsetAsync(out_pooled, 0, (size_t)N_GRAPHS * 768 * sizeof(float), stream);

    // CSR build
    count_deg<<<(N_EDGES + 255) / 256, 256, 0, stream>>>(edst, deg, N_EDGES);
    scan_block<<<NBLK, 256, 0, stream>>>(deg, row_start, bsum, N_NODES);
    scan_partials<<<1, 256, 0, stream>>>(bsum, boff, row_start, cursor, NBLK);
    add_offsets<<<NBLK, 256, 0, stream>>>(row_start, cursor, boff, N_NODES);
    fill_csr<<<(N_EDGES + 255) / 256, 256, 0, stream>>>(esrc, edst, cursor, srcs, N_EDGES);

    // all dtype converts in one kernel
    {
        const int n4 = N_NODES * F_IN / 4;  // 1,600,000 float4s
        const int tot = n4 + 360448;
        convert_all<<<(tot + 255) / 256, 256, 0, stream>>>(
            (const float4*)x, (uint2*)H, n4,
            w1[0], w1[1], w1[2], w2[0], w2[1], w2[2], Wall);
    }

    const int AGRID = (N_NODES + 3) / 4;      // 12500 (wave per node)
    const int GGRID = (N_NODES + 127) / 128;  // 391
    const int PBLK = (N_NODES + 63) / 64;     // 782
    for (int L = 0; L < 3; ++L) {
        int K1 = (L == 0) ? F_IN : DIM;
        float* sumsL = sums + L * 512;
        if (L == 0)
            aggregate_v2<128><<<AGRID, 256, 0, stream>>>(H, row_start, srcs, Abf, N_NODES);
        else
            aggregate_v2<256><<<AGRID, 256, 0, stream>>>(H, row_start, srcs, Abf, N_NODES);
        gemm_mfma<0><<<GGRID, 512, 0, stream>>>(Abf, W1t[L], b1[L], (void*)T, nullptr, N_NODES, K1);
        gemm_mfma<1><<<GGRID, 512, 0, stream>>>(T, W2t[L], b2[L], (void*)Mfp, sumsL, N_NODES, DIM);
        if (L < 2)
            bn_apply_pool<1><<<PBLK, 256, 0, stream>>>(Mfp, sumsL, bng[L], bnb[L], batch,
                                                       out_nodes, H, out_pooled, L * 256, N_NODES, 1.0f / N_NODES);
        else
            bn_apply_pool<0><<<PBLK, 256, 0, stream>>>(Mfp, sumsL, bng[L], bnb[L], batch,
                                                       out_nodes, H, out_pooled, L * 256, N_NODES, 1.0f / N_NODES);
    }
}

// Round 4
// 701.874 us; speedup vs baseline: 1.1667x; 1.0057x over previous
//
#include <hip/hip_runtime.h>

#define N_NODES 50000
#define N_EDGES 800000
#define F_IN 128
#define DIM 256
#define N_GRAPHS 512
#define BN_EPS 1e-5f

typedef unsigned short u16;
typedef unsigned int u32;
using floatx4 = __attribute__((ext_vector_type(4))) float;
using short8 = __attribute__((ext_vector_type(8))) short;

__device__ __forceinline__ u16 f2b(float f) {
    u32 u = __float_as_uint(f);
    return (u16)((u + 0x7fffu + ((u >> 16) & 1u)) >> 16);
}
__device__ __forceinline__ float blo(u32 u) { return __uint_as_float(u << 16); }
__device__ __forceinline__ float bhi(u32 u) { return __uint_as_float(u & 0xffff0000u); }
__device__ __forceinline__ u32 pack2(float a, float b) {
    return (u32)f2b(a) | ((u32)f2b(b) << 16);
}
__device__ __forceinline__ void load_lds16(const void* g, void* l) {
    __builtin_amdgcn_global_load_lds((const __attribute__((address_space(1))) void*)g,
                                     (__attribute__((address_space(3))) void*)l, 16, 0, 0);
}

// ---------------- CSR build ----------------

__global__ void count_deg(const int* __restrict__ dst, int* __restrict__ deg, int nE) {
    int e = blockIdx.x * 256 + threadIdx.x;
    if (e < nE) atomicAdd(&deg[dst[e]], 1);
}

__global__ void scan_block(const int* __restrict__ deg, int* __restrict__ row_start,
                           int* __restrict__ bsum, int n) {
    __shared__ int wtot[4];
    int i = blockIdx.x * 256 + threadIdx.x;
    int lane = threadIdx.x & 63, w = threadIdx.x >> 6;
    int v = (i < n) ? deg[i] : 0;
    int s = v;
#pragma unroll
    for (int d = 1; d < 64; d <<= 1) {
        int t = __shfl_up(s, d);
        if (lane >= d) s += t;
    }
    if (lane == 63) wtot[w] = s;
    __syncthreads();
    int off = 0;
#pragma unroll
    for (int k = 0; k < 4; ++k)
        if (k < w) off += wtot[k];
    s += off;
    if (i < n) row_start[i + 1] = s;
    if (threadIdx.x == 255) bsum[blockIdx.x] = s;
}

__global__ void scan_partials(const int* __restrict__ bsum, int* __restrict__ boff,
                              int* __restrict__ row_start, int* __restrict__ cursor, int nb) {
    __shared__ int wtot[4];
    int i = threadIdx.x;
    int lane = i & 63, w = i >> 6;
    int v = (i < nb) ? bsum[i] : 0;
    int s = v;
#pragma unroll
    for (int d = 1; d < 64; d <<= 1) {
        int t = __shfl_up(s, d);
        if (lane >= d) s += t;
    }
    if (lane == 63) wtot[w] = s;
    __syncthreads();
    int off = 0;
#pragma unroll
    for (int k = 0; k < 4; ++k)
        if (k < w) off += wtot[k];
    boff[i] = s + off - v;
    if (i == 0) { row_start[0] = 0; cursor[0] = 0; }
}

__global__ void add_offsets(int* __restrict__ row_start, int* __restrict__ cursor,
                            const int* __restrict__ boff, int n) {
    int i = blockIdx.x * 256 + threadIdx.x;
    if (i < n) {
        int fin = row_start[i + 1] + boff[blockIdx.x];
        row_start[i + 1] = fin;
        cursor[i + 1] = fin;
    }
}

__global__ void fill_csr(const int* __restrict__ src, const int* __restrict__ dst,
                         int* __restrict__ cursor, int* __restrict__ srcs, int nE) {
    int e = blockIdx.x * 256 + threadIdx.x;
    if (e < nE) {
        int p = atomicAdd(&cursor[dst[e]], 1);
        srcs[p] = src[e];
    }
}

// ---------------- one-shot converts: x -> bf16 H, all 6 weights -> transposed bf16 ----------------
// segment bases (u16 elems in Wall): w1_0@0 (K=128), w1_1@32768, w1_2@98304,
// w2_0@163840, w2_1@229376, w2_2@294912 ; total 360448

__global__ void convert_all(const float4* __restrict__ x4, uint2* __restrict__ Hout, int n4,
                            const float* __restrict__ w10, const float* __restrict__ w11,
                            const float* __restrict__ w12, const float* __restrict__ w20,
                            const float* __restrict__ w21, const float* __restrict__ w22,
                            u16* __restrict__ Wall) {
    int i = blockIdx.x * 256 + threadIdx.x;
    if (i < n4) {
        float4 v = x4[i];
        uint2 p;
        p.x = pack2(v.x, v.y);
        p.y = pack2(v.z, v.w);
        Hout[i] = p;
        return;
    }
    int j = i - n4;
    if (j >= 360448) return;
    const float* w;
    int K, base;
    if (j < 32768)       { w = w10; K = 128; base = 0; }
    else if (j < 98304)  { w = w11; K = 256; base = 32768; }
    else if (j < 163840) { w = w12; K = 256; base = 98304; }
    else if (j < 229376) { w = w20; K = 256; base = 163840; }
    else if (j < 294912) { w = w21; K = 256; base = 229376; }
    else                 { w = w22; K = 256; base = 294912; }
    int loc = j - base;
    int nn = loc / K, kk = loc - nn * K;
    Wall[j] = f2b(w[(size_t)kk * 256 + nn]);
}

// ---------------- aggregation v2 (bf16 gather): agg = h_i + sum_j h_j ----------------
// One wave per node. Multi-row gather instructions: lanes split into NSUB row-groups,
// each group reads a DIFFERENT neighbor row as uint4 (16B/lane) -> 1KiB per instruction.
// Per-lane partial sums folded with shfl_xor at the end.

template <int K>
__global__ __launch_bounds__(256) void aggregate_v2(
    const u16* __restrict__ h, const int* __restrict__ row_start,
    const int* __restrict__ srcs, u16* __restrict__ outp, int n) {
    constexpr int RW = K / 2;                 // u32 per row (128 or 64)
    constexpr int NSUB = (K == 256) ? 2 : 4;  // rows per gather instruction
    constexpr int NI = 8 / NSUB;              // instructions per 8-row batch
    int node = (int)(((size_t)blockIdx.x * blockDim.x + threadIdx.x) >> 6);
    int lane = threadIdx.x & 63;
    if (node >= n) return;
    const u32* hb = (const u32*)h;
    const int sub = lane / (64 / NSUB);       // row-group within the wave
    const int li = lane % (64 / NSUB);        // 16B chunk index within row

    float acc[8];
    {
        // self row: only the sub==0 lanes contribute (others init 0)
        uint4 v = make_uint4(0u, 0u, 0u, 0u);
        if (sub == 0) v = *(const uint4*)(hb + (size_t)node * RW + li * 4);
        acc[0] = blo(v.x); acc[1] = bhi(v.x);
        acc[2] = blo(v.y); acc[3] = bhi(v.y);
        acc[4] = blo(v.z); acc[5] = bhi(v.z);
        acc[6] = blo(v.w); acc[7] = bhi(v.w);
    }

    int s = row_start[node], e = row_start[node + 1];
    for (int j0 = s; j0 < e; j0 += 64) {
        int myidx = (j0 + lane < e) ? srcs[j0 + lane] : 0;
        int cnt = min(64, e - j0);
        int j = 0;
        for (; j + 7 < cnt; j += 8) {  // 8 neighbor rows in flight, NI instructions
            uint4 g[NI];
#pragma unroll
            for (int q = 0; q < NI; ++q) {
                int sq = __shfl(myidx, j + q * NSUB + sub);
                g[q] = *(const uint4*)(hb + (size_t)sq * RW + li * 4);
            }
#pragma unroll
            for (int q = 0; q < NI; ++q) {
                acc[0] += blo(g[q].x); acc[1] += bhi(g[q].x);
                acc[2] += blo(g[q].y); acc[3] += bhi(g[q].y);
                acc[4] += blo(g[q].z); acc[5] += bhi(g[q].z);
                acc[6] += blo(g[q].w); acc[7] += bhi(g[q].w);
            }
        }
        for (; j < cnt; j += NSUB) {  // predicated remainder, NSUB rows at a time
            int idx = j + sub;
            bool valid = idx < cnt;
            int sq = __shfl(myidx, valid ? idx : j);
            if (valid) {
                uint4 g = *(const uint4*)(hb + (size_t)sq * RW + li * 4);
                acc[0] += blo(g.x); acc[1] += bhi(g.x);
                acc[2] += blo(g.y); acc[3] += bhi(g.y);
                acc[4] += blo(g.z); acc[5] += bhi(g.z);
                acc[6] += blo(g.w); acc[7] += bhi(g.w);
            }
        }
    }

    // fold partial sums across row-groups
    if (NSUB == 4) {
#pragma unroll
        for (int t = 0; t < 8; ++t) acc[t] += __shfl_xor(acc[t], 16);
    }
#pragma unroll
    for (int t = 0; t < 8; ++t) acc[t] += __shfl_xor(acc[t], 32);

    if (sub == 0) {
        uint4 o;
        o.x = pack2(acc[0], acc[1]);
        o.y = pack2(acc[2], acc[3]);
        o.z = pack2(acc[4], acc[5]);
        o.w = pack2(acc[6], acc[7]);
        *(uint4*)((u32*)outp + (size_t)node * RW + li * 4) = o;
    }
}

// ---------------- bf16 MFMA GEMM, full-N: C(128x256) = relu(A @ Wt^T + bias) ----------------
// 512 threads = 8 waves (2 m x 4 n), wave tile 64x64 (4x4 frags of 16x16x32)
// MODE 0: C bf16 out.  MODE 1: C bf16 out + fused BN partial sums (stats computed on the
// quantized values so BN mean/var are exactly consistent with what bn_apply re-reads).

template <int MODE>
__global__ __launch_bounds__(512) void gemm_mfma(
    const u16* __restrict__ A, const u16* __restrict__ Bt, const float* __restrict__ bias,
    u16* __restrict__ Cout, float* __restrict__ sums, int M, int K) {
    __shared__ u16 As[128 * 32];
    __shared__ u16 Bs[256 * 32];
    const int tid = threadIdx.x;
    const int w = tid >> 6, lane = tid & 63;
    const int wm = w >> 2, wn = w & 3;
    const int r = lane & 15, rg = lane >> 4;
    const int bm = blockIdx.x * 128;

    floatx4 acc[4][4];
#pragma unroll
    for (int i = 0; i < 4; ++i)
#pragma unroll
        for (int j = 0; j < 4; ++j) acc[i][j] = (floatx4){0.f, 0.f, 0.f, 0.f};

    for (int k0 = 0; k0 < K; k0 += 32) {
        __syncthreads();
        {
            int arow = bm + (tid >> 2);
            if (arow >= M) arow = M - 1;
            load_lds16(A + (size_t)arow * K + k0 + (tid & 3) * 8, As + w * 512);
#pragma unroll
            for (int q = 0; q < 2; ++q) {
                int i = q * 512 + tid;
                int nrow = i >> 2;
                load_lds16(Bt + (size_t)nrow * K + k0 + (i & 3) * 8, Bs + (q * 8 + w) * 512);
            }
        }
        __syncthreads();
        short8 a[4], b[4];
#pragma unroll
        for (int mi = 0; mi < 4; ++mi)
            a[mi] = *(const short8*)(As + (wm * 64 + mi * 16 + r) * 32 + rg * 8);
#pragma unroll
        for (int ni = 0; ni < 4; ++ni)
            b[ni] = *(const short8*)(Bs + (wn * 64 + ni * 16 + r) * 32 + rg * 8);
#pragma unroll
        for (int mi = 0; mi < 4; ++mi)
#pragma unroll
            for (int ni = 0; ni < 4; ++ni)
                acc[mi][ni] = __builtin_amdgcn_mfma_f32_16x16x32_bf16(a[mi], b[ni], acc[mi][ni], 0, 0, 0);
    }

    if (MODE == 0) {
#pragma unroll
        for (int ni = 0; ni < 4; ++ni) {
            int col = wn * 64 + ni * 16 + r;
            float bv = bias[col];
#pragma unroll
            for (int mi = 0; mi < 4; ++mi)
#pragma unroll
                for (int rr = 0; rr < 4; ++rr) {
                    int row = bm + wm * 64 + mi * 16 + rg * 4 + rr;
                    if (row < M) Cout[(size_t)row * 256 + col] = f2b(fmaxf(acc[mi][ni][rr] + bv, 0.f));
                }
        }
    } else {
#pragma unroll
        for (int ni = 0; ni < 4; ++ni) {
            int col = wn * 64 + ni * 16 + r;
            float bv = bias[col];
            float s = 0.f, s2 = 0.f;
#pragma unroll
            for (int mi = 0; mi < 4; ++mi)
#pragma unroll
                for (int rr = 0; rr < 4; ++rr) {
                    int row = bm + wm * 64 + mi * 16 + rg * 4 + rr;
                    if (row < M) {
                        float v = fmaxf(acc[mi][ni][rr] + bv, 0.f);
                        u16 qb = f2b(v);
                        float vq = __uint_as_float((u32)qb << 16);
                        Cout[(size_t)row * 256 + col] = qb;
                        s += vq;
                        s2 += vq * vq;
                    }
                }
            s += __shfl_xor(s, 16);
            s += __shfl_xor(s, 32);
            s2 += __shfl_xor(s2, 16);
            s2 += __shfl_xor(s2, 32);
            if (rg == 0) {
                atomicAdd(&sums[col], s);
                atomicAdd(&sums[256 + col], s2);
            }
        }
    }
}

// ---------------- BN finalize+apply + bf16 re-pack + fused per-graph pooling ----------------
// Reads bf16 m (written by GEMM2), applies affine in fp32, writes fp32 out_nodes
// (nontemporal: never re-read) + bf16 H (next layer's gather input) + pooled atomics.

template <int WRITE_H>
__global__ void bn_apply_pool(const u16* __restrict__ Mb, const float* __restrict__ sums,
                              const float* __restrict__ g, const float* __restrict__ bb,
                              const int* __restrict__ batch, float* __restrict__ out_nodes,
                              u16* __restrict__ H, float* __restrict__ pooled,
                              int col_off, int n, float inv_n) {
    int w = threadIdx.x >> 6, lane = threadIdx.x & 63;
    int base = blockIdx.x * 64 + w * 16;
    if (base >= n) return;
    int c4 = lane << 2;
    float4 s1 = *(const float4*)(sums + c4);
    float4 s2 = *(const float4*)(sums + 256 + c4);
    float4 g4 = *(const float4*)(g + c4);
    float4 b4 = *(const float4*)(bb + c4);
    float4 sc, sh;
    {
        float mux = s1.x * inv_n, muy = s1.y * inv_n, muz = s1.z * inv_n, muw = s1.w * inv_n;
        sc.x = g4.x / sqrtf(s2.x * inv_n - mux * mux + BN_EPS);
        sc.y = g4.y / sqrtf(s2.y * inv_n - muy * muy + BN_EPS);
        sc.z = g4.z / sqrtf(s2.z * inv_n - muz * muz + BN_EPS);
        sc.w = g4.w / sqrtf(s2.w * inv_n - muw * muw + BN_EPS);
        sh.x = b4.x - mux * sc.x;
        sh.y = b4.y - muy * sc.y;
        sh.z = b4.z - muz * sc.z;
        sh.w = b4.w - muw * sc.w;
    }
    float4 acc = make_float4(0.f, 0.f, 0.f, 0.f);
    int gcur = -1;
    int end = min(base + 16, n);
    for (int row = base; row < end; ++row) {
        uint2 pk = *(const uint2*)(Mb + (size_t)row * 256 + c4);
        float4 o;
        o.x = fmaf(blo(pk.x), sc.x, sh.x);
        o.y = fmaf(bhi(pk.x), sc.y, sh.y);
        o.z = fmaf(blo(pk.y), sc.z, sh.z);
        o.w = fmaf(bhi(pk.y), sc.w, sh.w);
        floatx4 ov = {o.x, o.y, o.z, o.w};
        __builtin_nontemporal_store(ov, (floatx4*)(out_nodes + (size_t)row * 768 + col_off + c4));
        if (WRITE_H) {
            uint2 hk;
            hk.x = pack2(o.x, o.y);
            hk.y = pack2(o.z, o.w);
            *(uint2*)(H + (size_t)row * 256 + c4) = hk;
        }
        int gg = batch[row];
        if (gg != gcur) {
            if (gcur >= 0) {
                float* pp = pooled + (size_t)gcur * 768 + col_off + c4;
                atomicAdd(pp + 0, acc.x);
                atomicAdd(pp + 1, acc.y);
                atomicAdd(pp + 2, acc.z);
                atomicAdd(pp + 3, acc.w);
            }
            gcur = gg;
            acc = o;
        } else {
            acc.x += o.x; acc.y += o.y; acc.z += o.z; acc.w += o.w;
        }
    }
    if (gcur >= 0) {
        float* pp = pooled + (size_t)gcur * 768 + col_off + c4;
        atomicAdd(pp + 0, acc.x);
        atomicAdd(pp + 1, acc.y);
        atomicAdd(pp + 2, acc.z);
        atomicAdd(pp + 3, acc.w);
    }
}

// ---------------- launch ----------------

extern "C" void kernel_launch(void* const* d_in, const int* in_sizes, int n_in,
                              void* d_out, int out_size, void* d_ws, size_t ws_size,
                              hipStream_t stream) {
    const float* x = (const float*)d_in[0];
    const int* esrc = (const int*)d_in[1];
    const int* edst = esrc + N_EDGES;
    const int* batch = (const int*)d_in[2];

    const float* w1[3] = {(const float*)d_in[3], (const float*)d_in[9], (const float*)d_in[15]};
    const float* b1[3] = {(const float*)d_in[4], (const float*)d_in[10], (const float*)d_in[16]};
    const float* w2[3] = {(const float*)d_in[5], (const float*)d_in[11], (const float*)d_in[17]};
    const float* b2[3] = {(const float*)d_in[6], (const float*)d_in[12], (const float*)d_in[18]};
    const float* bng[3] = {(const float*)d_in[7], (const float*)d_in[13], (const float*)d_in[19]};
    const float* bnb[3] = {(const float*)d_in[8], (const float*)d_in[14], (const float*)d_in[20]};

    float* out_pooled = (float*)d_out;
    float* out_nodes = (float*)d_out + (size_t)N_GRAPHS * 768;

    char* p = (char*)d_ws;
    u16* Abf = (u16*)p; p += (size_t)N_NODES * 256 * 2;  // aggregate out AND gemm2 bf16 m out
    u16* T = (u16*)p;   p += (size_t)N_NODES * 256 * 2;  // GEMM1 out
    u16* H = (u16*)p;   p += (size_t)N_NODES * 256 * 2;  // bf16 node feats
    u16* Wall = (u16*)p; p += (size_t)360448 * 2;        // all transposed weights
    // zero region: [sums x3 | deg]  (one memset)
    float* sums = (float*)p; p += 3 * 512 * 4;
    int* deg = (int*)p;      p += (size_t)N_NODES * 4;
    const size_t zero_bytes = 3 * 512 * 4 + (size_t)N_NODES * 4;
    int* row_start = (int*)p; p += (size_t)(N_NODES + 1) * 4;
    int* cursor = (int*)p;    p += (size_t)(N_NODES + 1) * 4;
    int* srcs = (int*)p;      p += (size_t)N_EDGES * 4;
    int* bsum = (int*)p;      p += 256 * 4;
    int* boff = (int*)p;      p += 256 * 4;

    const u16* W1t[3] = {Wall, Wall + 32768, Wall + 98304};
    const u16* W2t[3] = {Wall + 163840, Wall + 229376, Wall + 294912};

    const int NBLK = (N_NODES + 255) / 256;  // 196

    hipMemsetAsync(sums, 0, zero_bytes, stream);
    hipMemsetAsync(out_pooled, 0, (size_t)N_GRAPHS * 768 * sizeof(float), stream);

    // CSR build
    count_deg<<<(N_EDGES + 255) / 256, 256, 0, stream>>>(edst, deg, N_EDGES);
    scan_block<<<NBLK, 256, 0, stream>>>(deg, row_start, bsum, N_NODES);
    scan_partials<<<1, 256, 0, stream>>>(bsum, boff, row_start, cursor, NBLK);
    add_offsets<<<NBLK, 256, 0, stream>>>(row_start, cursor, boff, N_NODES);
    fill_csr<<<(N_EDGES + 255) / 256, 256, 0, stream>>>(esrc, edst, cursor, srcs, N_EDGES);

    // all dtype converts in one kernel
    {
        const int n4 = N_NODES * F_IN / 4;  // 1,600,000 float4s
        const int tot = n4 + 360448;
        convert_all<<<(tot + 255) / 256, 256, 0, stream>>>(
            (const float4*)x, (uint2*)H, n4,
            w1[0], w1[1], w1[2], w2[0], w2[1], w2[2], Wall);
    }

    const int AGRID = (N_NODES + 3) / 4;      // 12500 (wave per node)
    const int GGRID = (N_NODES + 127) / 128;  // 391
    const int PBLK = (N_NODES + 63) / 64;     // 782
    for (int L = 0; L < 3; ++L) {
        int K1 = (L == 0) ? F_IN : DIM;
        float* sumsL = sums + L * 512;
        if (L == 0)
            aggregate_v2<128><<<AGRID, 256, 0, stream>>>(H, row_start, srcs, Abf, N_NODES);
        else
            aggregate_v2<256><<<AGRID, 256, 0, stream>>>(H, row_start, srcs, Abf, N_NODES);
        gemm_mfma<0><<<GGRID, 512, 0, stream>>>(Abf, W1t[L], b1[L], T, nullptr, N_NODES, K1);
        gemm_mfma<1><<<GGRID, 512, 0, stream>>>(T, W2t[L], b2[L], Abf, sumsL, N_NODES, DIM);
        if (L < 2)
            bn_apply_pool<1><<<PBLK, 256, 0, stream>>>(Abf, sumsL, bng[L], bnb[L], batch,
                                                       out_nodes, H, out_pooled, L * 256, N_NODES, 1.0f / N_NODES);
        else
            bn_apply_pool<0><<<PBLK, 256, 0, stream>>>(Abf, sumsL, bng[L], bnb[L], batch,
                                                       out_nodes, H, out_pooled, L * 256, N_NODES, 1.0f / N_NODES);
    }
}

// Round 5
// 698.866 us; speedup vs baseline: 1.1717x; 1.0043x over previous
//
#include <hip/hip_runtime.h>

#define N_NODES 50000
#define N_EDGES 800000
#define F_IN 128
#define DIM 256
#define N_GRAPHS 512
#define BN_EPS 1e-5f

typedef unsigned short u16;
typedef unsigned int u32;
using floatx4 = __attribute__((ext_vector_type(4))) float;
using short8 = __attribute__((ext_vector_type(8))) short;
using half2v = __attribute__((ext_vector_type(2))) _Float16;

#if __has_builtin(__builtin_amdgcn_fdot2)
#define HAS_FDOT2 1
#endif

// ---- fp16 helpers (IEEE half; RNE via v_cvt_f16_f32) ----
__device__ __forceinline__ u16 f2h(float f) {
    _Float16 h = (_Float16)f;
    return __builtin_bit_cast(u16, h);
}
__device__ __forceinline__ float hlo(u32 u) {
    half2v h = __builtin_bit_cast(half2v, u);
    return (float)h.x;
}
__device__ __forceinline__ float hhi(u32 u) {
    half2v h = __builtin_bit_cast(half2v, u);
    return (float)h.y;
}
__device__ __forceinline__ u32 pack2(float a, float b) {
    half2v h = {(_Float16)a, (_Float16)b};
    return __builtin_bit_cast(u32, h);
}
// accumulate both halves of a packed-f16 word into two fp32 accumulators.
// fdot2 path: 1 VALU op per feature (vs 2 for unpack+add).
__device__ __forceinline__ void dacc(u32 w, float& a, float& b) {
#ifdef HAS_FDOT2
    half2v v = __builtin_bit_cast(half2v, w);
    const half2v L = {(_Float16)1.0f, (_Float16)0.0f};
    const half2v Hm = {(_Float16)0.0f, (_Float16)1.0f};
    a = __builtin_amdgcn_fdot2(v, L, a, false);
    b = __builtin_amdgcn_fdot2(v, Hm, b, false);
#else
    a += hlo(w);
    b += hhi(w);
#endif
}
__device__ __forceinline__ void load_lds16(const void* g, void* l) {
    __builtin_amdgcn_global_load_lds((const __attribute__((address_space(1))) void*)g,
                                     (__attribute__((address_space(3))) void*)l, 16, 0, 0);
}

// ---------------- CSR build ----------------

__global__ void count_deg(const int* __restrict__ dst, int* __restrict__ deg, int nE) {
    int e = blockIdx.x * 256 + threadIdx.x;
    if (e < nE) atomicAdd(&deg[dst[e]], 1);
}

__global__ void scan_block(const int* __restrict__ deg, int* __restrict__ row_start,
                           int* __restrict__ bsum, int n) {
    __shared__ int wtot[4];
    int i = blockIdx.x * 256 + threadIdx.x;
    int lane = threadIdx.x & 63, w = threadIdx.x >> 6;
    int v = (i < n) ? deg[i] : 0;
    int s = v;
#pragma unroll
    for (int d = 1; d < 64; d <<= 1) {
        int t = __shfl_up(s, d);
        if (lane >= d) s += t;
    }
    if (lane == 63) wtot[w] = s;
    __syncthreads();
    int off = 0;
#pragma unroll
    for (int k = 0; k < 4; ++k)
        if (k < w) off += wtot[k];
    s += off;
    if (i < n) row_start[i + 1] = s;
    if (threadIdx.x == 255) bsum[blockIdx.x] = s;
}

__global__ void scan_partials(const int* __restrict__ bsum, int* __restrict__ boff,
                              int* __restrict__ row_start, int* __restrict__ cursor, int nb) {
    __shared__ int wtot[4];
    int i = threadIdx.x;
    int lane = i & 63, w = i >> 6;
    int v = (i < nb) ? bsum[i] : 0;
    int s = v;
#pragma unroll
    for (int d = 1; d < 64; d <<= 1) {
        int t = __shfl_up(s, d);
        if (lane >= d) s += t;
    }
    if (lane == 63) wtot[w] = s;
    __syncthreads();
    int off = 0;
#pragma unroll
    for (int k = 0; k < 4; ++k)
        if (k < w) off += wtot[k];
    boff[i] = s + off - v;
    if (i == 0) { row_start[0] = 0; cursor[0] = 0; }
}

__global__ void add_offsets(int* __restrict__ row_start, int* __restrict__ cursor,
                            const int* __restrict__ boff, int n) {
    int i = blockIdx.x * 256 + threadIdx.x;
    if (i < n) {
        int fin = row_start[i + 1] + boff[blockIdx.x];
        row_start[i + 1] = fin;
        cursor[i + 1] = fin;
    }
}

__global__ void fill_csr(const int* __restrict__ src, const int* __restrict__ dst,
                         int* __restrict__ cursor, int* __restrict__ srcs, int nE) {
    int e = blockIdx.x * 256 + threadIdx.x;
    if (e < nE) {
        int p = atomicAdd(&cursor[dst[e]], 1);
        srcs[p] = src[e];
    }
}

// ---------------- one-shot converts: x -> f16 H, all 6 weights -> transposed f16 ----------------
// segment bases (u16 elems in Wall): w1_0@0 (K=128), w1_1@32768, w1_2@98304,
// w2_0@163840, w2_1@229376, w2_2@294912 ; total 360448

__global__ void convert_all(const float4* __restrict__ x4, uint2* __restrict__ Hout, int n4,
                            const float* __restrict__ w10, const float* __restrict__ w11,
                            const float* __restrict__ w12, const float* __restrict__ w20,
                            const float* __restrict__ w21, const float* __restrict__ w22,
                            u16* __restrict__ Wall) {
    int i = blockIdx.x * 256 + threadIdx.x;
    if (i < n4) {
        float4 v = x4[i];
        uint2 p;
        p.x = pack2(v.x, v.y);
        p.y = pack2(v.z, v.w);
        Hout[i] = p;
        return;
    }
    int j = i - n4;
    if (j >= 360448) return;
    const float* w;
    int K, base;
    if (j < 32768)       { w = w10; K = 128; base = 0; }
    else if (j < 98304)  { w = w11; K = 256; base = 32768; }
    else if (j < 163840) { w = w12; K = 256; base = 98304; }
    else if (j < 229376) { w = w20; K = 256; base = 163840; }
    else if (j < 294912) { w = w21; K = 256; base = 229376; }
    else                 { w = w22; K = 256; base = 294912; }
    int loc = j - base;
    int nn = loc / K, kk = loc - nn * K;
    Wall[j] = f2h(w[(size_t)kk * 256 + nn]);
}

// ---------------- aggregation v3 (f16 gather + fdot2): agg = h_i + sum_j h_j ----------------
// One wave per node. Multi-row gather instructions: lanes split into NSUB row-groups,
// each group reads a DIFFERENT neighbor row as uint4 (16B/lane) -> 1KiB per instruction.
// Accumulation via v_dot2_f32_f16 (1 VALU op/feature). shfl_xor fold at the end.

template <int K>
__global__ __launch_bounds__(256) void aggregate_v2(
    const u16* __restrict__ h, const int* __restrict__ row_start,
    const int* __restrict__ srcs, u16* __restrict__ outp, int n) {
    constexpr int RW = K / 2;                 // u32 per row (128 or 64)
    constexpr int NSUB = (K == 256) ? 2 : 4;  // rows per gather instruction
    constexpr int NI = 8 / NSUB;              // instructions per 8-row batch
    int node = (int)(((size_t)blockIdx.x * blockDim.x + threadIdx.x) >> 6);
    int lane = threadIdx.x & 63;
    if (node >= n) return;
    const u32* hb = (const u32*)h;
    const int sub = lane / (64 / NSUB);       // row-group within the wave
    const int li = lane % (64 / NSUB);        // 16B chunk index within row

    float acc[8];
#pragma unroll
    for (int t = 0; t < 8; ++t) acc[t] = 0.f;
    {
        // self row: only the sub==0 lanes contribute (others stay 0)
        if (sub == 0) {
            uint4 v = *(const uint4*)(hb + (size_t)node * RW + li * 4);
            dacc(v.x, acc[0], acc[1]);
            dacc(v.y, acc[2], acc[3]);
            dacc(v.z, acc[4], acc[5]);
            dacc(v.w, acc[6], acc[7]);
        }
    }

    int s = row_start[node], e = row_start[node + 1];
    for (int j0 = s; j0 < e; j0 += 64) {
        int myidx = (j0 + lane < e) ? srcs[j0 + lane] : 0;
        int cnt = min(64, e - j0);
        int j = 0;
        for (; j + 7 < cnt; j += 8) {  // 8 neighbor rows in flight, NI instructions
            uint4 g[NI];
#pragma unroll
            for (int q = 0; q < NI; ++q) {
                int sq = __shfl(myidx, j + q * NSUB + sub);
                g[q] = *(const uint4*)(hb + (size_t)sq * RW + li * 4);
            }
#pragma unroll
            for (int q = 0; q < NI; ++q) {
                dacc(g[q].x, acc[0], acc[1]);
                dacc(g[q].y, acc[2], acc[3]);
                dacc(g[q].z, acc[4], acc[5]);
                dacc(g[q].w, acc[6], acc[7]);
            }
        }
        for (; j < cnt; j += NSUB) {  // predicated remainder, NSUB rows at a time
            int idx = j + sub;
            bool valid = idx < cnt;
            int sq = __shfl(myidx, valid ? idx : j);
            if (valid) {
                uint4 g = *(const uint4*)(hb + (size_t)sq * RW + li * 4);
                dacc(g.x, acc[0], acc[1]);
                dacc(g.y, acc[2], acc[3]);
                dacc(g.z, acc[4], acc[5]);
                dacc(g.w, acc[6], acc[7]);
            }
        }
    }

    // fold partial sums across row-groups
    if (NSUB == 4) {
#pragma unroll
        for (int t = 0; t < 8; ++t) acc[t] += __shfl_xor(acc[t], 16);
    }
#pragma unroll
    for (int t = 0; t < 8; ++t) acc[t] += __shfl_xor(acc[t], 32);

    if (sub == 0) {
        uint4 o;
        o.x = pack2(acc[0], acc[1]);
        o.y = pack2(acc[2], acc[3]);
        o.z = pack2(acc[4], acc[5]);
        o.w = pack2(acc[6], acc[7]);
        *(uint4*)((u32*)outp + (size_t)node * RW + li * 4) = o;
    }
}

// ---------------- f16 MFMA GEMM, full-N: C(128x256) = relu(A @ Wt^T + bias) ----------------
// 512 threads = 8 waves (2 m x 4 n), wave tile 64x64 (4x4 frags of 16x16x32)
// MODE 0: C f16 out.  MODE 1: C f16 out + fused BN partial sums (stats computed on the
// quantized values so BN mean/var are exactly consistent with what bn_apply re-reads).

template <int MODE>
__global__ __launch_bounds__(512) void gemm_mfma(
    const u16* __restrict__ A, const u16* __restrict__ Bt, const float* __restrict__ bias,
    u16* __restrict__ Cout, float* __restrict__ sums, int M, int K) {
    __shared__ u16 As[128 * 32];
    __shared__ u16 Bs[256 * 32];
    const int tid = threadIdx.x;
    const int w = tid >> 6, lane = tid & 63;
    const int wm = w >> 2, wn = w & 3;
    const int r = lane & 15, rg = lane >> 4;
    const int bm = blockIdx.x * 128;

    floatx4 acc[4][4];
#pragma unroll
    for (int i = 0; i < 4; ++i)
#pragma unroll
        for (int j = 0; j < 4; ++j) acc[i][j] = (floatx4){0.f, 0.f, 0.f, 0.f};

    for (int k0 = 0; k0 < K; k0 += 32) {
        __syncthreads();
        {
            int arow = bm + (tid >> 2);
            if (arow >= M) arow = M - 1;
            load_lds16(A + (size_t)arow * K + k0 + (tid & 3) * 8, As + w * 512);
#pragma unroll
            for (int q = 0; q < 2; ++q) {
                int i = q * 512 + tid;
                int nrow = i >> 2;
                load_lds16(Bt + (size_t)nrow * K + k0 + (i & 3) * 8, Bs + (q * 8 + w) * 512);
            }
        }
        __syncthreads();
        short8 a[4], b[4];
#pragma unroll
        for (int mi = 0; mi < 4; ++mi)
            a[mi] = *(const short8*)(As + (wm * 64 + mi * 16 + r) * 32 + rg * 8);
#pragma unroll
        for (int ni = 0; ni < 4; ++ni)
            b[ni] = *(const short8*)(Bs + (wn * 64 + ni * 16 + r) * 32 + rg * 8);
#pragma unroll
        for (int mi = 0; mi < 4; ++mi)
#pragma unroll
            for (int ni = 0; ni < 4; ++ni)
                acc[mi][ni] = __builtin_amdgcn_mfma_f32_16x16x32_f16(a[mi], b[ni], acc[mi][ni], 0, 0, 0);
    }

    if (MODE == 0) {
#pragma unroll
        for (int ni = 0; ni < 4; ++ni) {
            int col = wn * 64 + ni * 16 + r;
            float bv = bias[col];
#pragma unroll
            for (int mi = 0; mi < 4; ++mi)
#pragma unroll
                for (int rr = 0; rr < 4; ++rr) {
                    int row = bm + wm * 64 + mi * 16 + rg * 4 + rr;
                    if (row < M) Cout[(size_t)row * 256 + col] = f2h(fmaxf(acc[mi][ni][rr] + bv, 0.f));
                }
        }
    } else {
#pragma unroll
        for (int ni = 0; ni < 4; ++ni) {
            int col = wn * 64 + ni * 16 + r;
            float bv = bias[col];
            float s = 0.f, s2 = 0.f;
#pragma unroll
            for (int mi = 0; mi < 4; ++mi)
#pragma unroll
                for (int rr = 0; rr < 4; ++rr) {
                    int row = bm + wm * 64 + mi * 16 + rg * 4 + rr;
                    if (row < M) {
                        float v = fmaxf(acc[mi][ni][rr] + bv, 0.f);
                        u16 qb = f2h(v);
                        float vq = hlo((u32)qb);
                        Cout[(size_t)row * 256 + col] = qb;
                        s += vq;
                        s2 += vq * vq;
                    }
                }
            s += __shfl_xor(s, 16);
            s += __shfl_xor(s, 32);
            s2 += __shfl_xor(s2, 16);
            s2 += __shfl_xor(s2, 32);
            if (rg == 0) {
                atomicAdd(&sums[col], s);
                atomicAdd(&sums[256 + col], s2);
            }
        }
    }
}

// ---------------- BN finalize+apply + f16 re-pack + fused per-graph pooling ----------------
// Reads f16 m (written by GEMM2), applies affine in fp32, writes fp32 out_nodes
// (nontemporal: never re-read) + f16 H (next layer's gather input) + pooled atomics.

template <int WRITE_H>
__global__ void bn_apply_pool(const u16* __restrict__ Mb, const float* __restrict__ sums,
                              const float* __restrict__ g, const float* __restrict__ bb,
                              const int* __restrict__ batch, float* __restrict__ out_nodes,
                              u16* __restrict__ H, float* __restrict__ pooled,
                              int col_off, int n, float inv_n) {
    int w = threadIdx.x >> 6, lane = threadIdx.x & 63;
    int base = blockIdx.x * 64 + w * 16;
    if (base >= n) return;
    int c4 = lane << 2;
    float4 s1 = *(const float4*)(sums + c4);
    float4 s2 = *(const float4*)(sums + 256 + c4);
    float4 g4 = *(const float4*)(g + c4);
    float4 b4 = *(const float4*)(bb + c4);
    float4 sc, sh;
    {
        float mux = s1.x * inv_n, muy = s1.y * inv_n, muz = s1.z * inv_n, muw = s1.w * inv_n;
        sc.x = g4.x / sqrtf(s2.x * inv_n - mux * mux + BN_EPS);
        sc.y = g4.y / sqrtf(s2.y * inv_n - muy * muy + BN_EPS);
        sc.z = g4.z / sqrtf(s2.z * inv_n - muz * muz + BN_EPS);
        sc.w = g4.w / sqrtf(s2.w * inv_n - muw * muw + BN_EPS);
        sh.x = b4.x - mux * sc.x;
        sh.y = b4.y - muy * sc.y;
        sh.z = b4.z - muz * sc.z;
        sh.w = b4.w - muw * sc.w;
    }
    float4 acc = make_float4(0.f, 0.f, 0.f, 0.f);
    int gcur = -1;
    int end = min(base + 16, n);
    for (int row = base; row < end; ++row) {
        uint2 pk = *(const uint2*)(Mb + (size_t)row * 256 + c4);
        float4 o;
        o.x = fmaf(hlo(pk.x), sc.x, sh.x);
        o.y = fmaf(hhi(pk.x), sc.y, sh.y);
        o.z = fmaf(hlo(pk.y), sc.z, sh.z);
        o.w = fmaf(hhi(pk.y), sc.w, sh.w);
        floatx4 ov = {o.x, o.y, o.z, o.w};
        __builtin_nontemporal_store(ov, (floatx4*)(out_nodes + (size_t)row * 768 + col_off + c4));
        if (WRITE_H) {
            uint2 hk;
            hk.x = pack2(o.x, o.y);
            hk.y = pack2(o.z, o.w);
            *(uint2*)(H + (size_t)row * 256 + c4) = hk;
        }
        int gg = batch[row];
        if (gg != gcur) {
            if (gcur >= 0) {
                float* pp = pooled + (size_t)gcur * 768 + col_off + c4;
                atomicAdd(pp + 0, acc.x);
                atomicAdd(pp + 1, acc.y);
                atomicAdd(pp + 2, acc.z);
                atomicAdd(pp + 3, acc.w);
            }
            gcur = gg;
            acc = o;
        } else {
            acc.x += o.x; acc.y += o.y; acc.z += o.z; acc.w += o.w;
        }
    }
    if (gcur >= 0) {
        float* pp = pooled + (size_t)gcur * 768 + col_off + c4;
        atomicAdd(pp + 0, acc.x);
        atomicAdd(pp + 1, acc.y);
        atomicAdd(pp + 2, acc.z);
        atomicAdd(pp + 3, acc.w);
    }
}

// ---------------- launch ----------------

extern "C" void kernel_launch(void* const* d_in, const int* in_sizes, int n_in,
                              void* d_out, int out_size, void* d_ws, size_t ws_size,
                              hipStream_t stream) {
    const float* x = (const float*)d_in[0];
    const int* esrc = (const int*)d_in[1];
    const int* edst = esrc + N_EDGES;
    const int* batch = (const int*)d_in[2];

    const float* w1[3] = {(const float*)d_in[3], (const float*)d_in[9], (const float*)d_in[15]};
    const float* b1[3] = {(const float*)d_in[4], (const float*)d_in[10], (const float*)d_in[16]};
    const float* w2[3] = {(const float*)d_in[5], (const float*)d_in[11], (const float*)d_in[17]};
    const float* b2[3] = {(const float*)d_in[6], (const float*)d_in[12], (const float*)d_in[18]};
    const float* bng[3] = {(const float*)d_in[7], (const float*)d_in[13], (const float*)d_in[19]};
    const float* bnb[3] = {(const float*)d_in[8], (const float*)d_in[14], (const float*)d_in[20]};

    float* out_pooled = (float*)d_out;
    float* out_nodes = (float*)d_out + (size_t)N_GRAPHS * 768;

    char* p = (char*)d_ws;
    u16* Abf = (u16*)p; p += (size_t)N_NODES * 256 * 2;  // aggregate out AND gemm2 f16 m out
    u16* T = (u16*)p;   p += (size_t)N_NODES * 256 * 2;  // GEMM1 out
    u16* H = (u16*)p;   p += (size_t)N_NODES * 256 * 2;  // f16 node feats
    u16* Wall = (u16*)p; p += (size_t)360448 * 2;        // all transposed weights
    // zero region: [sums x3 | deg]  (one memset)
    float* sums = (float*)p; p += 3 * 512 * 4;
    int* deg = (int*)p;      p += (size_t)N_NODES * 4;
    const size_t zero_bytes = 3 * 512 * 4 + (size_t)N_NODES * 4;
    int* row_start = (int*)p; p += (size_t)(N_NODES + 1) * 4;
    int* cursor = (int*)p;    p += (size_t)(N_NODES + 1) * 4;
    int* srcs = (int*)p;      p += (size_t)N_EDGES * 4;
    int* bsum = (int*)p;      p += 256 * 4;
    int* boff = (int*)p;      p += 256 * 4;

    const u16* W1t[3] = {Wall, Wall + 32768, Wall + 98304};
    const u16* W2t[3] = {Wall + 163840, Wall + 229376, Wall + 294912};

    const int NBLK = (N_NODES + 255) / 256;  // 196

    hipMemsetAsync(sums, 0, zero_bytes, stream);
    hipMemsetAsync(out_pooled, 0, (size_t)N_GRAPHS * 768 * sizeof(float), stream);

    // CSR build
    count_deg<<<(N_EDGES + 255) / 256, 256, 0, stream>>>(edst, deg, N_EDGES);
    scan_block<<<NBLK, 256, 0, stream>>>(deg, row_start, bsum, N_NODES);
    scan_partials<<<1, 256, 0, stream>>>(bsum, boff, row_start, cursor, NBLK);
    add_offsets<<<NBLK, 256, 0, stream>>>(row_start, cursor, boff, N_NODES);
    fill_csr<<<(N_EDGES + 255) / 256, 256, 0, stream>>>(esrc, edst, cursor, srcs, N_EDGES);

    // all dtype converts in one kernel
    {
        const int n4 = N_NODES * F_IN / 4;  // 1,600,000 float4s
        const int tot = n4 + 360448;
        convert_all<<<(tot + 255) / 256, 256, 0, stream>>>(
            (const float4*)x, (uint2*)H, n4,
            w1[0], w1[1], w1[2], w2[0], w2[1], w2[2], Wall);
    }

    const int AGRID = (N_NODES + 3) / 4;      // 12500 (wave per node)
    const int GGRID = (N_NODES + 127) / 128;  // 391
    const int PBLK = (N_NODES + 63) / 64;     // 782
    for (int L = 0; L < 3; ++L) {
        int K1 = (L == 0) ? F_IN : DIM;
        float* sumsL = sums + L * 512;
        if (L == 0)
            aggregate_v2<128><<<AGRID, 256, 0, stream>>>(H, row_start, srcs, Abf, N_NODES);
        else
            aggregate_v2<256><<<AGRID, 256, 0, stream>>>(H, row_start, srcs, Abf, N_NODES);
        gemm_mfma<0><<<GGRID, 512, 0, stream>>>(Abf, W1t[L], b1[L], T, nullptr, N_NODES, K1);
        gemm_mfma<1><<<GGRID, 512, 0, stream>>>(T, W2t[L], b2[L], Abf, sumsL, N_NODES, DIM);
        if (L < 2)
            bn_apply_pool<1><<<PBLK, 256, 0, stream>>>(Abf, sumsL, bng[L], bnb[L], batch,
                                                       out_nodes, H, out_pooled, L * 256, N_NODES, 1.0f / N_NODES);
        else
            bn_apply_pool<0><<<PBLK, 256, 0, stream>>>(Abf, sumsL, bng[L], bnb[L], batch,
                                                       out_nodes, H, out_pooled, L * 256, N_NODES, 1.0f / N_NODES);
    }
}